// Round 8
// baseline (316.551 us; speedup 1.0000x reference)
//
#include <hip/hip_runtime.h>

#define NF 768
#define D1 10
#define D2 128
#define BM 64

typedef __attribute__((ext_vector_type(8))) short bf16x8;
typedef __attribute__((ext_vector_type(16))) float f32x16;

static __device__ __forceinline__ float sigf(float v){ return 1.0f/(1.0f+__expf(-v)); }
static __device__ __forceinline__ float tanhfast(float v){ return 2.0f/(1.0f+__expf(-2.0f*v)) - 1.0f; }
static __device__ __forceinline__ short f2bf(float f){
    unsigned u = __float_as_uint(f);
    u += 0x7fffu + ((u>>16)&1u);
    return (short)(u>>16);
}

// async global->LDS, 16B per lane, LDS dest = wave-uniform base + lane*16
static __device__ __forceinline__ void gload16(const void* g, void* l){
    __builtin_amdgcn_global_load_lds(
        (const __attribute__((address_space(1))) unsigned int*)(unsigned long long)g,
        (__attribute__((address_space(3))) unsigned int*)(unsigned long long)l,
        16, 0, 0);
}

static __device__ __forceinline__ bf16x8 cvt8(float4 a, float4 b){
    unsigned u0,u1,u2,u3;
    asm("v_cvt_pk_bf16_f32 %0, %1, %2" : "=v"(u0) : "v"(a.x), "v"(a.y));
    asm("v_cvt_pk_bf16_f32 %0, %1, %2" : "=v"(u1) : "v"(a.z), "v"(a.w));
    asm("v_cvt_pk_bf16_f32 %0, %1, %2" : "=v"(u2) : "v"(b.x), "v"(b.y));
    asm("v_cvt_pk_bf16_f32 %0, %1, %2" : "=v"(u3) : "v"(b.z), "v"(b.w));
    union { unsigned u[4]; bf16x8 v; } r;
    r.u[0]=u0; r.u[1]=u1; r.u[2]=u2; r.u[3]=u3;
    return r.v;
}

// ---- degree counts ----
__global__ void k_deg(const int* __restrict__ dst, int* __restrict__ cnt, int E){
    int e = blockIdx.x*256 + threadIdx.x;
    if(e<E) atomicAdd(&cnt[dst[e]], 1);
}

// ---- scan (rowptr/rowcur) + dinv fused, single block ----
__global__ __launch_bounds__(256) void k_scan(const int* __restrict__ cnt,
                                              int* __restrict__ rowptr, int* __restrict__ rowcur,
                                              float* __restrict__ dinv, int N, int E){
    __shared__ int part[256];
    int t = threadIdx.x;
    int C = (N+255)/256;
    int lo = t*C, hi = lo+C; if(hi>N) hi=N; if(lo>N) lo=N;
    int s=0;
    for(int i=lo;i<hi;i++) s += cnt[i];
    part[t]=s;
    __syncthreads();
    if(t==0){
        int run=0;
        for(int i=0;i<256;i++){ int v=part[i]; part[i]=run; run+=v; }
        rowptr[N]=E;
    }
    __syncthreads();
    int run = part[t];
    for(int i=lo;i<hi;i++){
        rowptr[i]=run; rowcur[i]=run; run += cnt[i];
        dinv[i] = rsqrtf((float)cnt[i] + 1.0f);
    }
}

__global__ void k_fill(const int* __restrict__ src, const int* __restrict__ dst,
                       const float* __restrict__ dinv, int* __restrict__ rowcur,
                       int* __restrict__ esrc, float* __restrict__ enorm, int E){
    int e = blockIdx.x*256 + threadIdx.x;
    if(e>=E) return;
    int s=src[e], d=dst[e];
    int pos = atomicAdd(&rowcur[d], 1);
    esrc[pos]=s;
    enorm[pos]=dinv[s]*dinv[d];
}

// ---- h1 = x @ W1 ----
__global__ __launch_bounds__(256) void k_h1(const float* __restrict__ x,
                                            const float* __restrict__ W1,
                                            float* __restrict__ h1, int N){
    __shared__ float wt[D1*NF];
    for(int idx=threadIdx.x; idx<NF*D1; idx+=256){
        int k=idx/D1, c=idx-k*D1;
        wt[c*NF+k]=W1[idx];
    }
    __syncthreads();
    int row = blockIdx.x*4 + (threadIdx.x>>6);
    int lane = threadIdx.x&63;
    if(row>=N) return;
    const float4* xr = (const float4*)(x + (size_t)row*NF);
    float acc[D1];
#pragma unroll
    for(int c=0;c<D1;c++) acc[c]=0.f;
#pragma unroll
    for(int i=0;i<3;i++){
        float4 v = xr[lane + 64*i];
#pragma unroll
        for(int c=0;c<D1;c++){
            float4 w = *(const float4*)&wt[c*NF + (lane+64*i)*4];
            acc[c] += v.x*w.x + v.y*w.y + v.z*w.z + v.w*w.w;
        }
    }
#pragma unroll
    for(int c=0;c<D1;c++){
        float v=acc[c];
#pragma unroll
        for(int off=32;off;off>>=1) v += __shfl_down(v,off,64);
        acc[c]=v;
    }
    if(lane==0){
#pragma unroll
        for(int c=0;c<D1;c++) h1[(size_t)row*D1+c]=acc[c];
    }
}

// ---- layer-1 CSR gather + relu ----
__global__ __launch_bounds__(256) void k_gath1(const float* __restrict__ h1,
        const int* __restrict__ rowptr, const int* __restrict__ esrc,
        const float* __restrict__ enorm, const float* __restrict__ dinv,
        const float* __restrict__ b1, float* __restrict__ h, int N){
    int node = blockIdx.x*4 + (threadIdx.x>>6);
    int lane = threadIdx.x&63;
    if(node>=N) return;
    int e0=rowptr[node], e1=rowptr[node+1];
    float acc[D1];
#pragma unroll
    for(int c=0;c<D1;c++) acc[c]=0.f;
    for(int e=e0+lane; e<e1; e+=64){
        int s=esrc[e]; float w=enorm[e];
        const float* hr = h1 + (size_t)s*D1;
#pragma unroll
        for(int c=0;c<D1;c++) acc[c] += hr[c]*w;
    }
    if(lane==0){
        float di=dinv[node], d2=di*di;
        const float* hr = h1 + (size_t)node*D1;
#pragma unroll
        for(int c=0;c<D1;c++) acc[c] += hr[c]*d2;
    }
#pragma unroll
    for(int c=0;c<D1;c++){
        float v=acc[c];
#pragma unroll
        for(int off=32;off;off>>=1) v += __shfl_down(v,off,64);
        acc[c]=v;
    }
    if(lane==0){
#pragma unroll
        for(int c=0;c<D1;c++){
            float v = acc[c] + b1[c];
            h[(size_t)node*D1+c] = v>0.f ? v : 0.f;
        }
    }
}

__global__ __launch_bounds__(128) void k_hz(const float* __restrict__ h,
                                            const float* __restrict__ W2,
                                            float* __restrict__ hz, int N){
    __shared__ float w2s[D1*D2];
    int j = threadIdx.x;
    for(int i=j;i<D1*D2;i+=128) w2s[i]=W2[i];
    __syncthreads();
    int n = blockIdx.x;
    if(n>=N) return;
    const float* hr = h + (size_t)n*D1;
    float acc=0.f;
#pragma unroll
    for(int k=0;k<D1;k++) acc += hr[k]*w2s[k*D2+j];
    hz[(size_t)n*D2+j]=acc;
}

// ---- layer-2 CSR gather (fused zfin), writes fp32 z table ----
__global__ __launch_bounds__(128) void k_gath2(const float* __restrict__ hz,
        const int* __restrict__ rowptr, const int* __restrict__ esrc,
        const float* __restrict__ enorm, const float* __restrict__ dinv,
        const float* __restrict__ b2, float* __restrict__ zbf, int N){
    int n = blockIdx.x;
    int c = threadIdx.x;
    int e0 = rowptr[n], e1 = rowptr[n+1];
    float di = dinv[n];
    float acc = hz[(size_t)n*D2+c]*di*di + b2[c];
    int e = e0;
    for(; e+1<e1; e+=2){
        int s0=esrc[e], s1=esrc[e+1];
        float w0=enorm[e], w1=enorm[e+1];
        acc += hz[(size_t)s0*D2+c]*w0 + hz[(size_t)s1*D2+c]*w1;
    }
    if(e<e1) acc += hz[(size_t)esrc[e]*D2+c]*enorm[e];
    zbf[(size_t)n*D2+c] = acc;
}

// ---- B fragment image over FULL K=1024: 12 frags x 64 ks16 x 64 lanes x 8 bf16 ----
__global__ void k_wimgB(const float* __restrict__ Wih, ushort* __restrict__ img){
    int gid = blockIdx.x*256 + threadIdx.x;        // 12*64*64 = 49152
    if(gid >= 12*64*64) return;
    int l = gid & 63;
    int ks16 = (gid>>6) & 63;
    int f = gid >> 12;
    int dd = l & 31, kb = l>>5;
    int wn = f/3, gi = f - wn*3;
    int gbase = (gi==0)?0:((gi==1)?256:384);
    int wrow = gbase + wn*32 + dd;
    int k = ks16*16 + kb*8;
    const float* p = Wih + (size_t)wrow*1024 + k;
    float4 v0=*(const float4*)p, v1=*(const float4*)(p+4);
    bf16x8 o;
    o[0]=f2bf(v0.x); o[1]=f2bf(v0.y); o[2]=f2bf(v0.z); o[3]=f2bf(v0.w);
    o[4]=f2bf(v1.x); o[5]=f2bf(v1.y); o[6]=f2bf(v1.z); o[7]=f2bf(v1.w);
    *(bf16x8*)(img + (size_t)gid*8) = o;
}

// ---- fused MFMA GEMM + LSTM. K=1024 feat = [z_h|r_emb|z_t].
// A: fp32 via global_load_lds into 4-deep LDS ring. B: L2 image into
// double-buffered registers, issued BEFORE the A-gloads each chunk so
// compiler B-waits never drain the A HBM stream (single vmcnt counter). ----
__global__ __launch_bounds__(256,2) void k_big(
    const float* __restrict__ remb, const ushort* __restrict__ img,
    const float* __restrict__ zbf, const float* __restrict__ b_ih,
    const float* __restrict__ b_hh, const int* __restrict__ trip,
    float* __restrict__ score, int T)
{
    __shared__ float ring[4][64*64];   // 4 x 16 KB
    int tid=threadIdx.x, lane=tid&63, w=tid>>6;
    int l31=lane&31, lh=lane>>5;
    int t0=blockIdx.x*BM;

    // staging geometry: wave w stages rows [w*16, w*16+16), 4 issues of 4 rows
    const int l16 = lane>>4;           // row within 4-row group
    int tc4[4], th4[4], tt4[4], lsl[4];
#pragma unroll
    for(int j=0;j<4;j++){
        int row = w*16 + j*4 + l16;
        int tc = t0 + row; if(tc>=T) tc=T-1;
        tc4[j] = tc;
        th4[j] = trip[3*tc];
        tt4[j] = trip[3*tc+2];
        lsl[j] = ((lane&15) ^ (row&15))*4;   // pre-swizzled source slot (floats)
    }

    const ushort* wb0 = img + ((size_t)(w*3+0)*64*64 + lane)*8;
    const ushort* wb1 = img + ((size_t)(w*3+1)*64*64 + lane)*8;
    const ushort* wb2 = img + ((size_t)(w*3+2)*64*64 + lane)*8;
    const int base0 = l31*64;
    const int base1 = (32+l31)*64;
    const int rx = lane&15;

    f32x16 acc[2][3];
    const f32x16 zer = {0,0,0,0,0,0,0,0,0,0,0,0,0,0,0,0};
#pragma unroll
    for(int m=0;m<2;m++)
#pragma unroll
        for(int g=0;g<3;g++) acc[m][g]=zer;

    bf16x8 qb[2][4][3];   // [chunk parity][kstep][frag] — all static indices

#define BISSUE(CN_) if((CN_)<16){ \
    _Pragma("unroll") \
    for(int s_=0;s_<4;s_++){ \
        size_t ko_ = (size_t)((CN_)*4+s_)*512; \
        qb[(CN_)&1][s_][0] = *(const bf16x8*)(wb0+ko_); \
        qb[(CN_)&1][s_][1] = *(const bf16x8*)(wb1+ko_); \
        qb[(CN_)&1][s_][2] = *(const bf16x8*)(wb2+ko_); \
    } }

#define ISSUE(C_) { \
    float* dst_ = &ring[(C_)&3][(w*16)*64]; \
    _Pragma("unroll") \
    for(int j_=0;j_<4;j_++){ \
        const float* src_; \
        if((C_)<2)       src_ = zbf + (size_t)th4[j_]*D2 + (C_)*64 + lsl[j_]; \
        else if((C_)<14) src_ = remb + (size_t)tc4[j_]*NF + ((C_)-2)*64 + lsl[j_]; \
        else             src_ = zbf + (size_t)tt4[j_]*D2 + ((C_)-14)*64 + lsl[j_]; \
        gload16(src_, dst_ + j_*256); \
    } }

#define KSTEP(C_,S_) { \
    const float4 a00_ = *(const float4*)&cur_[base0 + ((((S_)*4+lh*2)  )^rx)*4]; \
    const float4 a01_ = *(const float4*)&cur_[base0 + ((((S_)*4+lh*2)+1)^rx)*4]; \
    bf16x8 A0_ = cvt8(a00_, a01_); \
    const float4 a10_ = *(const float4*)&cur_[base1 + ((((S_)*4+lh*2)  )^rx)*4]; \
    const float4 a11_ = *(const float4*)&cur_[base1 + ((((S_)*4+lh*2)+1)^rx)*4]; \
    bf16x8 A1_ = cvt8(a10_, a11_); \
    acc[0][0]=__builtin_amdgcn_mfma_f32_32x32x16_bf16(A0_,qb[(C_)&1][S_][0],acc[0][0],0,0,0); \
    acc[0][1]=__builtin_amdgcn_mfma_f32_32x32x16_bf16(A0_,qb[(C_)&1][S_][1],acc[0][1],0,0,0); \
    acc[0][2]=__builtin_amdgcn_mfma_f32_32x32x16_bf16(A0_,qb[(C_)&1][S_][2],acc[0][2],0,0,0); \
    acc[1][0]=__builtin_amdgcn_mfma_f32_32x32x16_bf16(A1_,qb[(C_)&1][S_][0],acc[1][0],0,0,0); \
    acc[1][1]=__builtin_amdgcn_mfma_f32_32x32x16_bf16(A1_,qb[(C_)&1][S_][1],acc[1][1],0,0,0); \
    acc[1][2]=__builtin_amdgcn_mfma_f32_32x32x16_bf16(A1_,qb[(C_)&1][S_][2],acc[1][2],0,0,0); \
}

// wait W = exact count of VMEM ops issued after chunk C's A-gloads
#define CHUNK(C_,W_) { \
    asm volatile("s_waitcnt vmcnt(" W_ ")" ::: "memory"); \
    __builtin_amdgcn_sched_barrier(0); \
    __builtin_amdgcn_s_barrier(); \
    BISSUE((C_)+1) \
    __builtin_amdgcn_sched_barrier(0); \
    if((C_)+3 < 16) { ISSUE((C_)+3) } \
    __builtin_amdgcn_sched_barrier(0); \
    const float* cur_ = &ring[(C_)&3][0]; \
    __builtin_amdgcn_s_setprio(1); \
    KSTEP(C_,0) KSTEP(C_,1) KSTEP(C_,2) KSTEP(C_,3) \
    __builtin_amdgcn_s_setprio(0); \
}

    // prologue: B(0) first, then 3 A-chunks in flight
    BISSUE(0)
    __builtin_amdgcn_sched_barrier(0);
    ISSUE(0) ISSUE(1) ISSUE(2)

    CHUNK(0 ,"8")  CHUNK(1 ,"20") CHUNK(2 ,"32") CHUNK(3 ,"32")
    CHUNK(4 ,"32") CHUNK(5 ,"32") CHUNK(6 ,"32") CHUNK(7 ,"32")
    CHUNK(8 ,"32") CHUNK(9 ,"32") CHUNK(10,"32") CHUNK(11,"32")
    CHUNK(12,"32") CHUNK(13,"32") CHUNK(14,"28") CHUNK(15,"24")
#undef CHUNK
#undef KSTEP
#undef ISSUE
#undef BISSUE

    // ---- epilogue: bias + LSTM + row-sum reduce (reuse ring[0] as rowsum) ----
    float* rowsum = &ring[0][0];
    __syncthreads();
    if(tid<BM) rowsum[tid]=0.f;
    __syncthreads();
    int d = w*32+l31;
    float bi=b_ih[d]+b_hh[d];
    float bg=b_ih[256+d]+b_hh[256+d];
    float bo=b_ih[384+d]+b_hh[384+d];
#pragma unroll
    for(int m=0;m<2;m++){
#pragma unroll
        for(int r=0;r<16;r++){
            int row = m*32 + (r&3)+8*(r>>2)+4*lh;
            float ig = acc[m][0][r] + bi;
            float gg = acc[m][1][r] + bg;
            float og = acc[m][2][r] + bo;
            float cc = sigf(ig)*tanhfast(gg);
            float ov = sigf(og)*tanhfast(cc);
#pragma unroll
            for(int off=1; off<32; off<<=1) ov += __shfl_xor(ov, off, 64);
            if(l31==0) atomicAdd(&rowsum[row], ov);
        }
    }
    __syncthreads();
    if(tid < BM){
        int t = t0 + tid;
        if(t < T) score[t] = sigf(rowsum[tid]);
    }
}

extern "C" void kernel_launch(void* const* d_in, const int* in_sizes, int n_in,
                              void* d_out, int out_size, void* d_ws, size_t ws_size,
                              hipStream_t stream){
    const float* x    = (const float*)d_in[0];
    const float* remb = (const float*)d_in[1];
    const float* W1   = (const float*)d_in[2];
    const float* b1   = (const float*)d_in[3];
    const float* W2   = (const float*)d_in[4];
    const float* b2   = (const float*)d_in[5];
    const float* Wih  = (const float*)d_in[6];
    const float* b_ih = (const float*)d_in[8];
    const float* b_hh = (const float*)d_in[9];
    const int*   ei   = (const int*)d_in[10];
    const int*   trip = (const int*)d_in[11];
    float* score = (float*)d_out;

    const int N = in_sizes[0]/NF;       // 15000
    const int E = in_sizes[10]/2;       // 200000
    const int T = in_sizes[11]/3;       // 100000
    const int* src = ei;
    const int* dst = ei + E;

    float* ws = (float*)d_ws;
    size_t o = 0;
    ushort* img  = (ushort*)(ws+o); o += (size_t)12*64*64*8/2;   // 786 KB
    float* zbf   = ws+o;            o += (size_t)N*D2;           // fp32 z, 7.7 MB
    int*   cnt    = (int*)(ws+o);   o += (size_t)((N+8)&~7);
    int*   rowptr = (int*)(ws+o);   o += (size_t)((N+8)&~7);
    int*   rowcur = (int*)(ws+o);   o += (size_t)((N+8)&~7);
    int*   esrc   = (int*)(ws+o);   o += (size_t)E;
    float* enorm  = ws+o;           o += (size_t)E;
    float* dinv   = ws+o;           o += (size_t)((N+7)&~7);
    float* h1     = ws+o;           o += (size_t)N*D1;
    float* hbuf   = ws+o;           o += (size_t)N*D1;
    float* hz     = ws+o;           o += (size_t)N*D2;
    (void)ws_size; (void)n_in; (void)out_size;

    hipMemsetAsync(cnt, 0, (size_t)N*sizeof(int), stream);

    k_wimgB<<<dim3((12*64*64+255)/256), dim3(256), 0, stream>>>(Wih, img);
    k_deg  <<<dim3((E+255)/256), dim3(256), 0, stream>>>(dst, cnt, E);
    k_scan <<<dim3(1), dim3(256), 0, stream>>>(cnt, rowptr, rowcur, dinv, N, E);
    k_fill <<<dim3((E+255)/256), dim3(256), 0, stream>>>(src, dst, dinv, rowcur, esrc, enorm, E);
    k_h1   <<<dim3((N+3)/4), dim3(256), 0, stream>>>(x, W1, h1, N);
    k_gath1<<<dim3((N+3)/4), dim3(256), 0, stream>>>(h1, rowptr, esrc, enorm, dinv, b1, hbuf, N);
    k_hz   <<<dim3(N), dim3(128), 0, stream>>>(hbuf, W2, hz, N);
    k_gath2<<<dim3(N), dim3(128), 0, stream>>>(hz, rowptr, esrc, enorm, dinv, b2, zbf, N);
    k_big  <<<dim3((T+BM-1)/BM), dim3(256), 0, stream>>>(remb, img, zbf, b_ih, b_hh, trip, score, T);
}